// Round 4
// baseline (5663.883 us; speedup 1.0000x reference)
//
#include <hip/hip_runtime.h>
#include <math.h>

// Problem constants
#define TLEN    960000          // samples per batch
#define BATCH   16
#define KF      144000          // filter length (KP taps + the appended 1.0)
#define KP      143999          // ir_param length
#define ROW     1104384         // KF + TLEN + pad (max in-row index used = 1104319)
#define HRP_PAD 512
#define HRPL    145536          // 512 front pad + KF + back pad (max frag idx 145,053)
#define NGQ     94              // groups per K-quarter (12 chunks each)
#define UNROLL  12
#define QCH     1128            // chunks per quarter (4 quarters * 1128 = 4512 = band KF+384)

typedef __attribute__((ext_vector_type(8))) short bf16x8;
typedef __attribute__((ext_vector_type(4))) float f32x4;

__device__ __forceinline__ unsigned short f2bf(float f) {
  unsigned int u = __float_as_uint(f);
  u += 0x7FFFu + ((u >> 16) & 1u);   // RNE
  return (unsigned short)(u >> 16);
}

// 8 shifted copies of the reversed filter hr = [tanh(ir_param), 1.0], zero-padded.
// hrp[m][i] = hrval(i - 512 - m); copy m gives every lane a 16B-aligned fragment start.
// Out-of-range taps (t<0 or t>KP) are 0, so over-band fragments contribute nothing.
__global__ __launch_bounds__(256) void build_hrp_kernel(const float* __restrict__ irp,
                                                        unsigned short* __restrict__ hrp) {
  int idx = blockIdx.x * 256 + threadIdx.x;
  if (idx >= 8 * HRPL) return;
  int m = idx / HRPL;
  int i = idx - m * HRPL;
  int t = i - HRP_PAD - m;
  unsigned short v = 0;
  if (t >= 0 && t <= KP) {
    v = (t == KP) ? (unsigned short)0x3F80 /*1.0 bf16*/ : f2bf(tanhf(irp[t]));
  }
  hrp[idx] = v;
}

// Zero-padded bf16 input: xbp[b][i] = bf16(x[b][i - KF]) for valid range, 0 in the
// KF-long causal front pad and the prefetch tail pad.
__global__ __launch_bounds__(256) void build_xbp_kernel(const float* __restrict__ x,
                                                        unsigned short* __restrict__ xbp) {
  int idx = blockIdx.x * 256 + threadIdx.x;
  if (idx >= BATCH * ROW) return;
  int b = idx / ROW;
  int i = idx - b * ROW;
  float v = 0.f;
  int s = i - KF;
  if (s >= 0 && s < TLEN) v = x[b * TLEN + s];
  xbp[idx] = f2bf(v);
}

// Block = one 256-output tile (all 16 batches); its 4 waves each cover one K-quarter
// (1128 chunks of 32). Per chunk: 16 MFMAs share one A-fragment; 2 fresh Toeplitz
// filter fragments enter a 24-slot rotating FIFO.
//
// FIFO algebra (verified vs R2's content formula A(r,c)=fp+16*(2c-r)):
//   consumption: acc[r] at chunk c uses slot (2c+16-r) mod 24
//   refill:      at chunk c load content 16*(2c+8) -> slot (2c) mod 24
//                            and content 16*(2c+9) -> slot (2c+1) mod 24
//   => every fragment is loaded 4..12 chunks before first use (~2500+ cyc slack at
//      MFMA-bound pace, covers HBM-miss 900 cyc). R3's 16-slot FIFO had a 1-chunk lag
//      -> one L2/L3 latency paid per chunk -> MfmaUtil 31%.
// Slot (2c+1)'s old content dies as this chunk's FIRST MFMA (acc[15]); refills are
// placed after acc[15]/acc[14]. A prefetched 6 chunks ahead (6-slot ring, unroll 12).
// Registers: F 96 + acc 64 + aR 24 + addr ~ 210 arch -> 2 waves/SIMD (same as R3).
__global__ __launch_bounds__(256, 2) void conv_main_kernel(const unsigned short* __restrict__ xbp,
                                                           const unsigned short* __restrict__ hrp,
                                                           float* __restrict__ out) {
  const int tid  = threadIdx.x;
  const int wv   = tid >> 6;        // K-quarter index 0..3
  const int lane = tid & 63;
  const int l15  = lane & 15;       // A: batch row ; B/D: column
  const int quad = lane >> 4;
  const int Tw   = blockIdx.x * 256;   // this block's first output sample
  const int cq   = wv * QCH;           // first chunk of this wave's K-quarter

  // x fragment pointer: A[m=l15][k] = xbp[l15][Tw + 32*(cq+c) + quad*8 + j]
  const unsigned short* ap = xbp + l15 * ROW + Tw + cq * 32 + quad * 8;

  // filter fragment base. Copy m = E0&7 -> every 16B load is aligned.
  const int E0 = 511 - l15 + 8 * quad;
  const int m  = E0 & 7;
  const unsigned short* fp = hrp + m * HRPL + (E0 + m) + cq * 32;

  // Init: fill all 24 slots with contents alpha = -15..8 (slot (alpha+16) mod 24).
  bf16x8 F[24];
#pragma unroll
  for (int w = -15; w <= 8; ++w) F[(w + 16) % 24] = *(const bf16x8*)(fp + 16 * w);

  bf16x8 aR[6];
#pragma unroll
  for (int i = 0; i < 6; ++i) aR[i] = *(const bf16x8*)(ap + 32 * i);

  f32x4 acc[16] = {};

  for (int g = 0; g < NGQ; ++g) {
    const unsigned short* fg = fp + g * 384;   // 16 * 24g : filter content base
    const unsigned short* ag = ap + g * 384;   // 32 * 12g : x chunk base
#pragma unroll
    for (int u = 0; u < UNROLL; ++u) {
      bf16x8 a = aR[u % 6];
      // first two MFMAs retire the slots being refilled this chunk
      acc[15] = __builtin_amdgcn_mfma_f32_16x16x32_bf16(a, F[(2*u+ 1)%24], acc[15], 0,0,0);
      acc[14] = __builtin_amdgcn_mfma_f32_16x16x32_bf16(a, F[(2*u+ 2)%24], acc[14], 0,0,0);
      F[(2*u    )%24] = *(const bf16x8*)(fg + 16*(2*u+8));   // content 2c+8
      F[(2*u + 1)%24] = *(const bf16x8*)(fg + 16*(2*u+9));   // content 2c+9
      aR[u % 6]       = *(const bf16x8*)(ag + 32*(u+6));     // x prefetch, +6 chunks
      acc[13] = __builtin_amdgcn_mfma_f32_16x16x32_bf16(a, F[(2*u+ 3)%24], acc[13], 0,0,0);
      acc[12] = __builtin_amdgcn_mfma_f32_16x16x32_bf16(a, F[(2*u+ 4)%24], acc[12], 0,0,0);
      acc[11] = __builtin_amdgcn_mfma_f32_16x16x32_bf16(a, F[(2*u+ 5)%24], acc[11], 0,0,0);
      acc[10] = __builtin_amdgcn_mfma_f32_16x16x32_bf16(a, F[(2*u+ 6)%24], acc[10], 0,0,0);
      acc[ 9] = __builtin_amdgcn_mfma_f32_16x16x32_bf16(a, F[(2*u+ 7)%24], acc[ 9], 0,0,0);
      acc[ 8] = __builtin_amdgcn_mfma_f32_16x16x32_bf16(a, F[(2*u+ 8)%24], acc[ 8], 0,0,0);
      acc[ 7] = __builtin_amdgcn_mfma_f32_16x16x32_bf16(a, F[(2*u+ 9)%24], acc[ 7], 0,0,0);
      acc[ 6] = __builtin_amdgcn_mfma_f32_16x16x32_bf16(a, F[(2*u+10)%24], acc[ 6], 0,0,0);
      acc[ 5] = __builtin_amdgcn_mfma_f32_16x16x32_bf16(a, F[(2*u+11)%24], acc[ 5], 0,0,0);
      acc[ 4] = __builtin_amdgcn_mfma_f32_16x16x32_bf16(a, F[(2*u+12)%24], acc[ 4], 0,0,0);
      acc[ 3] = __builtin_amdgcn_mfma_f32_16x16x32_bf16(a, F[(2*u+13)%24], acc[ 3], 0,0,0);
      acc[ 2] = __builtin_amdgcn_mfma_f32_16x16x32_bf16(a, F[(2*u+14)%24], acc[ 2], 0,0,0);
      acc[ 1] = __builtin_amdgcn_mfma_f32_16x16x32_bf16(a, F[(2*u+15)%24], acc[ 1], 0,0,0);
      acc[ 0] = __builtin_amdgcn_mfma_f32_16x16x32_bf16(a, F[(2*u+16)%24], acc[ 0], 0,0,0);
    }
  }

  // Deterministic cross-quarter reduce in LDS. Wave 0 writes, 1..2 add,
  // wave 3 adds its partial and stores. Lane stride 4B -> 2-way aliasing, free.
  __shared__ float red[4096];
#pragma unroll
  for (int s = 0; s < 3; ++s) {
    if (wv == s) {
#pragma unroll
      for (int r = 0; r < 16; ++r) {
#pragma unroll
        for (int k = 0; k < 4; ++k) {
          int idx = (r * 4 + k) * 64 + lane;
          if (s == 0) red[idx] = acc[r][k];
          else        red[idx] += acc[r][k];
        }
      }
    }
    __syncthreads();
  }
  if (wv == 3) {
    // C/D layout: col = lane&15 (t), row = quad*4 + reg (batch)
#pragma unroll
    for (int r = 0; r < 16; ++r) {
      int t = Tw + 16 * r + l15;
#pragma unroll
      for (int k = 0; k < 4; ++k) {
        out[(quad * 4 + k) * TLEN + t] = red[(r * 4 + k) * 64 + lane] + acc[r][k];
      }
    }
  }
}

extern "C" void kernel_launch(void* const* d_in, const int* in_sizes, int n_in,
                              void* d_out, int out_size, void* d_ws, size_t ws_size,
                              hipStream_t stream) {
  const float* x   = (const float*)d_in[0];   // (16,1,960000) f32
  const float* irp = (const float*)d_in[1];   // (1,1,143999) f32
  float* out = (float*)d_out;                 // (16,1,960000) f32

  // workspace: [ hrp: 8*HRPL bf16 = 2,328,576 B | xbp: 16*ROW bf16 = 35,340,288 B ]
  unsigned short* hrp = (unsigned short*)d_ws;
  unsigned short* xbp = (unsigned short*)((char*)d_ws + (size_t)(8 * HRPL) * 2);

  build_hrp_kernel<<<(8 * HRPL + 255) / 256, 256, 0, stream>>>(irp, hrp);
  build_xbp_kernel<<<(BATCH * ROW + 255) / 256, 256, 0, stream>>>(x, xbp);
  // 3750 tiles of 256 outputs; block = 4 waves = 4 K-quarters of one tile
  conv_main_kernel<<<3750, 256, 0, stream>>>(xbp, hrp, out);
}

// Round 5
// 2815.790 us; speedup vs baseline: 2.0115x; 2.0115x over previous
//
#include <hip/hip_runtime.h>
#include <math.h>

// Problem constants
#define TLEN    960000          // samples per batch
#define BATCH   16
#define KF      144000          // filter length (KP taps + appended 1.0)
#define KP      143999          // ir_param length
#define HRPL    145536          // per shifted filter copy: 512 front pad + KF + back pad
#define NI      1104704         // padded x row length (KF + TLEN + tail pad, mult of 8)
#define NTILE   938             // ceil(960000 / 1024) output tiles of 1024
#define QCH     1128            // chunks per K-quarter (4*1128*32 = KF+384 band)
#define NGQ     47              // groups per quarter (24 chunks each)
#define GCH     24              // chunks per group
#define CPYSTR  1552            // LDS filter copy stride (elems) = 1536 + 16 pad (bank spread)
#define FBUFE   12416           // one F staging buffer: 8 copies * 1552 elems
#define W0OFF   256             // window start = 32*C0 + 256

typedef __attribute__((ext_vector_type(8))) short bf16x8;
typedef __attribute__((ext_vector_type(4))) float f32x4;

__device__ __forceinline__ unsigned short f2bf(float f) {
  unsigned int u = __float_as_uint(f);
  u += 0x7FFFu + ((u >> 16) & 1u);   // RNE
  return (unsigned short)(u >> 16);
}

// async global->LDS, 16B per lane: LDS dest = uniform base + lane*16 (m104/m108)
__device__ __forceinline__ void gl_lds16(const unsigned short* g, unsigned short* l) {
  __builtin_amdgcn_global_load_lds((const __attribute__((address_space(1))) void*)g,
                                   (__attribute__((address_space(3))) void*)l, 16, 0, 0);
}

// 8 shifted copies of reversed filter hr = [tanh(ir_param), 1.0]: hrp[m][i] = hrval(i-512-m).
__global__ __launch_bounds__(256) void build_hrp_kernel(const float* __restrict__ irp,
                                                        unsigned short* __restrict__ hrp) {
  int idx = blockIdx.x * 256 + threadIdx.x;
  if (idx >= 8 * HRPL) return;
  int m = idx / HRPL;
  int i = idx - m * HRPL;
  int t = i - 512 - m;
  unsigned short v = 0;
  if (t >= 0 && t <= KP) {
    v = (t == KP) ? (unsigned short)0x3F80 /*1.0*/ : f2bf(tanhf(irp[t]));
  }
  hrp[idx] = v;
}

// Chunk-major bf16 x: xbp2[u*128 + b*8 + j] = xpad(b, 8u+j), xpad(b,i) = x[b][i-KF] or 0.
// Makes every A-fragment load a contiguous 1KB: addr = base + lane*16B.
__global__ __launch_bounds__(256) void build_xbp2_kernel(const float* __restrict__ x,
                                                         unsigned short* __restrict__ xbp2) {
  int idx = blockIdx.x * 256 + threadIdx.x;
  if (idx >= NI * BATCH) return;
  int u = idx >> 7;
  int r = idx & 127;
  int b = r >> 3;
  int j = idx & 7;
  int i = (u << 3) | j;
  float v = 0.f;
  int s = i - KF;
  if (s >= 0 && s < TLEN) v = x[b * TLEN + s];
  xbp2[idx] = f2bf(v);
}

__global__ __launch_bounds__(256) void zero_out_kernel(float4* __restrict__ out4) {
  int idx = blockIdx.x * 256 + threadIdx.x;   // 15,000*256 = 3,840,000 = exactly out/4
  out4[idx] = make_float4(0.f, 0.f, 0.f, 0.f);
}

// Block = 4 waves = 4 adjacent 256-output tiles, SAME K-quarter (filter fragments are
// identical across waves). Grid = 938 tiles x 4 quarters; quarter partials accumulate
// into pre-zeroed out via f32 atomicAdd.
// Per 24-chunk group: block stages 8 shifted-filter copies x 1536 elems (3KB) into LDS
// via global_load_lds (async, double-buffered, 6 full-wave instrs per wave). Per chunk:
// 16 MFMAs share one A-fragment (contiguous 1KB global load, ring-2); 2 fresh filter
// fragments ds_read_b128 into the 16-slot FIFO (slot = content-index alpha mod 16,
// refill alpha = 2C+1, 2C+2 -> ~2-chunk use distance; at 3 waves/SIMD = ~450 cyc wall).
__global__ __launch_bounds__(256, 3) void conv_main_kernel(const unsigned short* __restrict__ xbp2,
                                                           const unsigned short* __restrict__ hrp,
                                                           float* __restrict__ out) {
  const int tid  = threadIdx.x;
  const int wv   = tid >> 6;
  const int lane = tid & 63;
  const int l15  = lane & 15;       // A: batch row ; B/D: column
  const int quad = lane >> 4;

  const int bid  = blockIdx.x;
  const int Q    = bid / NTILE;          // K-quarter 0..3
  const int tile = bid - Q * NTILE;      // output tile 0..937
  const int C0   = Q * QCH;              // first absolute chunk of this quarter

  // ---- A addressing (chunk-major xbp2): elem = (Tw8 + 4C + q)*128 + l15*8
  const int Tw8 = tile * 128 + wv * 32;  // (tile*1024 + wv*256)/8
  const unsigned short* aP = xbp2 + ((Tw8 + quad) * 128 + l15 * 8) + C0 * 512;

  // ---- F lane constants. Copy m = (-E0)&7 => (E0+m) % 8 == 0 (true 16B alignment).
  const int E0 = 511 - l15 + 8 * quad;
  const int m  = (-E0) & 7;
  const int fo = m * CPYSTR + (E0 + m - W0OFF);   // lane's elem offset inside a buffer

  __shared__ unsigned short fbuf[2 * FBUFE];      // 49,664 B

  // ---- stage group 0 (wave wv stages copies 2wv, 2wv+1; 3 x 512 elems each)
  const int j0 = 2 * wv, j1 = 2 * wv + 1;
  {
    const int W = C0 * 32 + W0OFF;
#pragma unroll
    for (int h = 0; h < 3; ++h) {
      gl_lds16(hrp + j0 * HRPL + W + h * 512 + lane * 8, fbuf + j0 * CPYSTR + h * 512);
      gl_lds16(hrp + j1 * HRPL + W + h * 512 + lane * 8, fbuf + j1 * CPYSTR + h * 512);
    }
  }
  // A ring preload (independent of LDS)
  bf16x8 A0 = *(const bf16x8*)(aP);
  bf16x8 A1 = *(const bf16x8*)(aP + 512);

  __syncthreads();   // buffer 0 staged

  // ---- FIFO preload: contents alpha = 2C0-15 .. 2C0 (slot = alpha mod 16; 2C0 % 16 == 0)
  bf16x8 F[16];
  {
    const unsigned short* fb0 = fbuf + fo;
#pragma unroll
    for (int a = -15; a <= 0; ++a) F[a & 15] = *(const bf16x8*)(fb0 + 16 * a);
  }

  f32x4 acc[16] = {};

  for (int g = 0; g < NGQ; ++g) {
    if (g < NGQ - 1) {   // stage group g+1 into the other buffer (async)
      const int W = C0 * 32 + W0OFF + (g + 1) * 768;
      unsigned short* db = fbuf + ((g + 1) & 1) * FBUFE;
#pragma unroll
      for (int h = 0; h < 3; ++h) {
        gl_lds16(hrp + j0 * HRPL + W + h * 512 + lane * 8, db + j0 * CPYSTR + h * 512);
        gl_lds16(hrp + j1 * HRPL + W + h * 512 + lane * 8, db + j1 * CPYSTR + h * 512);
      }
    }
    const unsigned short* fbL = fbuf + (g & 1) * FBUFE + fo;
    for (int h = 0; h < 3; ++h) {
      const unsigned short* fh = fbL + 256 * h;   // refill elem off = 32c + 16*delta, c = 8h+cc
#pragma unroll
      for (int cc = 0; cc < 8; ++cc) {
        bf16x8 a = (cc & 1) ? A1 : A0;
        // consumption: acc[r] <- slot (2cc + 16 - r) mod 16 ; retire the two refill slots first
        acc[15] = __builtin_amdgcn_mfma_f32_16x16x32_bf16(a, F[(2*cc+ 1)&15], acc[15], 0,0,0);
        acc[14] = __builtin_amdgcn_mfma_f32_16x16x32_bf16(a, F[(2*cc+ 2)&15], acc[14], 0,0,0);
        F[(2*cc+1)&15] = *(const bf16x8*)(fh + 32*cc + 16);   // content alpha = 2C+1
        F[(2*cc+2)&15] = *(const bf16x8*)(fh + 32*cc + 32);   // content alpha = 2C+2
        if (cc & 1) A1 = *(const bf16x8*)(aP + 1024);         // A refill: chunk C+2
        else        A0 = *(const bf16x8*)(aP + 1024);
        acc[13] = __builtin_amdgcn_mfma_f32_16x16x32_bf16(a, F[(2*cc+ 3)&15], acc[13], 0,0,0);
        acc[12] = __builtin_amdgcn_mfma_f32_16x16x32_bf16(a, F[(2*cc+ 4)&15], acc[12], 0,0,0);
        acc[11] = __builtin_amdgcn_mfma_f32_16x16x32_bf16(a, F[(2*cc+ 5)&15], acc[11], 0,0,0);
        acc[10] = __builtin_amdgcn_mfma_f32_16x16x32_bf16(a, F[(2*cc+ 6)&15], acc[10], 0,0,0);
        acc[ 9] = __builtin_amdgcn_mfma_f32_16x16x32_bf16(a, F[(2*cc+ 7)&15], acc[ 9], 0,0,0);
        acc[ 8] = __builtin_amdgcn_mfma_f32_16x16x32_bf16(a, F[(2*cc+ 8)&15], acc[ 8], 0,0,0);
        acc[ 7] = __builtin_amdgcn_mfma_f32_16x16x32_bf16(a, F[(2*cc+ 9)&15], acc[ 7], 0,0,0);
        acc[ 6] = __builtin_amdgcn_mfma_f32_16x16x32_bf16(a, F[(2*cc+10)&15], acc[ 6], 0,0,0);
        acc[ 5] = __builtin_amdgcn_mfma_f32_16x16x32_bf16(a, F[(2*cc+11)&15], acc[ 5], 0,0,0);
        acc[ 4] = __builtin_amdgcn_mfma_f32_16x16x32_bf16(a, F[(2*cc+12)&15], acc[ 4], 0,0,0);
        acc[ 3] = __builtin_amdgcn_mfma_f32_16x16x32_bf16(a, F[(2*cc+13)&15], acc[ 3], 0,0,0);
        acc[ 2] = __builtin_amdgcn_mfma_f32_16x16x32_bf16(a, F[(2*cc+14)&15], acc[ 2], 0,0,0);
        acc[ 1] = __builtin_amdgcn_mfma_f32_16x16x32_bf16(a, F[(2*cc+15)&15], acc[ 1], 0,0,0);
        acc[ 0] = __builtin_amdgcn_mfma_f32_16x16x32_bf16(a, F[(2*cc+16)&15], acc[ 0], 0,0,0);
        aP += 512;
      }
    }
    __syncthreads();   // drains this wave's stage(g+1) + all waves done reading buf g
  }

  // ---- epilogue: accumulate quarter partial. C/D: col = l15 (t), row = quad*4 + k (batch)
  const int Twave = tile * 1024 + wv * 256;
#pragma unroll
  for (int r = 0; r < 16; ++r) {
    int t = Twave + 16 * r + l15;
    if (t < TLEN) {
#pragma unroll
      for (int k = 0; k < 4; ++k) {
        atomicAdd(&out[(quad * 4 + k) * TLEN + t], acc[r][k]);
      }
    }
  }
}

extern "C" void kernel_launch(void* const* d_in, const int* in_sizes, int n_in,
                              void* d_out, int out_size, void* d_ws, size_t ws_size,
                              hipStream_t stream) {
  const float* x   = (const float*)d_in[0];   // (16,1,960000) f32
  const float* irp = (const float*)d_in[1];   // (1,1,143999) f32
  float* out = (float*)d_out;                 // (16,1,960000) f32

  // ws: [ hrp: 8*HRPL bf16 = 2,328,576 B | xbp2: NI*16 bf16 = 35,350,528 B ] = 37.68 MB
  unsigned short* hrp  = (unsigned short*)d_ws;
  unsigned short* xbp2 = (unsigned short*)((char*)d_ws + (size_t)(8 * HRPL) * 2);

  build_hrp_kernel<<<(8 * HRPL + 255) / 256, 256, 0, stream>>>(irp, hrp);
  build_xbp2_kernel<<<(NI * BATCH + 255) / 256, 256, 0, stream>>>(x, xbp2);
  zero_out_kernel<<<15000, 256, 0, stream>>>((float4*)out);
  // 938 tiles x 4 K-quarters; block = 4 waves = 4 adjacent 256-output tiles, shared filter
  conv_main_kernel<<<NTILE * 4, 256, 0, stream>>>(xbp2, hrp, out);
}